// Round 1
// baseline (13165.929 us; speedup 1.0000x reference)
//
#include <hip/hip_runtime.h>
#include <hip/hip_bf16.h>
#include <math.h>

// Problem constants
#define BB 16
#define TT 512
#define FF 40
#define CC 256
#define HH 256
#define GG 768   // 3*H
#define NB 16

// Workspace layout (float offsets). gi aliases out1 (out1 dead after conv2).
#define O_OUT1 0u                       // [b][h][c][8]  16*512*256*8 = 16777216
#define O_GI   0u                       // [bt][768]     6291456 (aliases out1)
#define O_OUT2 16777216u                // [b][h][c][2]  4194304
#define O_OUT3 20971520u                // [b][h][c]     2097152  (== feats[b][t][c])
#define O_W2T  23068672u                // [ci*25+kh*5+kw][co] 1638400
#define O_W3T  24707072u                // 1638400
#define O_WIHT 26345472u                // [c][g] 196608
#define O_HBUF 26542080u                // 2 * 16*256 = 8192
// total 26550272 floats = 106.2 MB

// ---------------- weight transposes ----------------
__global__ void transpose_w_kernel(const float* __restrict__ w, float* __restrict__ wt) {
    // w[co][r] (r = ci*25+kh*5+kw, 6400) -> wt[r*256 + co]
    int e = blockIdx.x * 256 + threadIdx.x;   // e = r*256+co, grid 6400
    int r = e >> 8, co = e & 255;
    wt[e] = w[co * 6400 + r];
}

__global__ void transpose_wih_kernel(const float* __restrict__ wih, float* __restrict__ wiht) {
    int g = blockIdx.x;          // 768
    int c = threadIdx.x;         // 256
    wiht[c * 768 + g] = wih[g * 256 + c];
}

// ---------------- conv block 1 ----------------
// x (16,512,40) -> out1 [b][h][c][8]
__global__ __launch_bounds__(256) void conv1_kernel(
    const float* __restrict__ x, const float* __restrict__ w1,
    const float* __restrict__ b1, const float* __restrict__ g1,
    const float* __restrict__ bt1, const float* __restrict__ m1,
    const float* __restrict__ v1, float* __restrict__ out1) {
    int h = blockIdx.x;          // 512
    int b = blockIdx.y;          // 16
    int c = threadIdx.x;         // 256
    __shared__ float xs[5][44];
    int t = threadIdx.x;
    if (t < 220) {
        int rr = t / 44, cc = t % 44;
        int hh = h + rr - 2, ww = cc - 2;
        float v = 0.f;
        if (hh >= 0 && hh < TT && ww >= 0 && ww < FF) v = x[(b * TT + hh) * FF + ww];
        xs[rr][cc] = v;
    }
    __syncthreads();
    float wr[25];
#pragma unroll
    for (int i = 0; i < 25; ++i) wr[i] = w1[c * 25 + i];
    float sc = g1[c] * rsqrtf(v1[c] + 1e-5f);
    float sh = (b1[c] - m1[c]) * sc + bt1[c];
    float conv[40];
#pragma unroll
    for (int w = 0; w < 40; ++w) conv[w] = 0.f;
#pragma unroll
    for (int kh = 0; kh < 5; ++kh) {
        float rr[44];
#pragma unroll
        for (int i = 0; i < 44; ++i) rr[i] = xs[kh][i];
#pragma unroll
        for (int kw = 0; kw < 5; ++kw) {
            float wv = wr[kh * 5 + kw];
#pragma unroll
            for (int w = 0; w < 40; ++w) conv[w] += rr[w + kw] * wv;
        }
    }
    float* op = out1 + (((size_t)(b * TT + h) * CC) + c) * 8;
#pragma unroll
    for (int j = 0; j < 8; ++j) {
        float m = 0.f;   // relu folded into pool (max with 0)
#pragma unroll
        for (int p = 0; p < 5; ++p) m = fmaxf(m, conv[j * 5 + p] * sc + sh);
        op[j] = m;
    }
}

// ---------------- conv block 2 ----------------
// out1 [b][h][ci][8] -> out2 [b][h][co][2]
__global__ __launch_bounds__(256) void conv2_kernel(
    const float* __restrict__ in, const float* __restrict__ w2t,
    const float* __restrict__ b2, const float* __restrict__ g2,
    const float* __restrict__ bt2, const float* __restrict__ m2,
    const float* __restrict__ v2, float* __restrict__ out2) {
    int htile = blockIdx.x;                 // 128
    int b = blockIdx.y;                     // 16
    int co = blockIdx.z * 64 + (threadIdx.x & 63);
    int h = htile * 4 + (threadIdx.x >> 6);
    float acc[8];
#pragma unroll
    for (int w = 0; w < 8; ++w) acc[w] = 0.f;
    for (int ci = 0; ci < CC; ++ci) {
        const float* wb = w2t + (size_t)ci * 25 * 256 + co;
#pragma unroll
        for (int kh = 0; kh < 5; ++kh) {
            int hh = h + kh - 2;
            float4 ra, rb;
            if (hh >= 0 && hh < TT) {
                const float4* ip = (const float4*)(in + (((size_t)(b * TT + hh) * CC) + ci) * 8);
                ra = ip[0]; rb = ip[1];
            } else {
                ra = make_float4(0.f, 0.f, 0.f, 0.f); rb = ra;
            }
            float rin[8] = {ra.x, ra.y, ra.z, ra.w, rb.x, rb.y, rb.z, rb.w};
#pragma unroll
            for (int kw = 0; kw < 5; ++kw) {
                float wv = wb[(kh * 5 + kw) * 256];
#pragma unroll
                for (int w = 0; w < 8; ++w) {
                    int idx = w + kw - 2;
                    if (idx >= 0 && idx < 8) acc[w] += rin[idx] * wv;
                }
            }
        }
    }
    float sc = g2[co] * rsqrtf(v2[co] + 1e-5f);
    float sh = (b2[co] - m2[co]) * sc + bt2[co];
    float p0 = 0.f, p1 = 0.f;
#pragma unroll
    for (int w = 0; w < 4; ++w) p0 = fmaxf(p0, acc[w] * sc + sh);
#pragma unroll
    for (int w = 4; w < 8; ++w) p1 = fmaxf(p1, acc[w] * sc + sh);
    float2* op = (float2*)(out2 + (((size_t)(b * TT + h) * CC) + co) * 2);
    *op = make_float2(p0, p1);
}

// ---------------- conv block 3 ----------------
// out2 [b][h][ci][2] -> out3 [b][h][co]  (== feats[b][t][c])
__global__ __launch_bounds__(256) void conv3_kernel(
    const float* __restrict__ in, const float* __restrict__ w3t,
    const float* __restrict__ b3, const float* __restrict__ g3,
    const float* __restrict__ bt3, const float* __restrict__ m3,
    const float* __restrict__ v3, float* __restrict__ out3) {
    int htile = blockIdx.x;
    int b = blockIdx.y;
    int co = blockIdx.z * 64 + (threadIdx.x & 63);
    int h = htile * 4 + (threadIdx.x >> 6);
    float a0 = 0.f, a1 = 0.f;
    for (int ci = 0; ci < CC; ++ci) {
        const float* wb = w3t + (size_t)ci * 25 * 256 + co;
#pragma unroll
        for (int kh = 0; kh < 5; ++kh) {
            int hh = h + kh - 2;
            float i0 = 0.f, i1 = 0.f;
            if (hh >= 0 && hh < TT) {
                float2 rv = *(const float2*)(in + (((size_t)(b * TT + hh) * CC) + ci) * 2);
                i0 = rv.x; i1 = rv.y;
            }
            float wv1 = wb[(kh * 5 + 1) * 256];
            float wv2 = wb[(kh * 5 + 2) * 256];
            float wv3 = wb[(kh * 5 + 3) * 256];
            // w=0: kernel taps kw=2,3 hit cols 0,1 ; w=1: kw=1,2 hit cols 0,1
            a0 += i0 * wv2 + i1 * wv3;
            a1 += i0 * wv1 + i1 * wv2;
        }
    }
    float sc = g3[co] * rsqrtf(v3[co] + 1e-5f);
    float sh = (b3[co] - m3[co]) * sc + bt3[co];
    float r0 = fmaxf(0.f, a0 * sc + sh);
    float r1 = fmaxf(0.f, a1 * sc + sh);
    out3[((size_t)(b * TT + h) * CC) + co] = fmaxf(r0, r1);
}

// ---------------- gi_all GEMM ----------------
// gi[bt][g] = b_ih[g] + sum_c feats[bt][c] * w_iht[c][g]
__global__ __launch_bounds__(256) void gi_kernel(
    const float* __restrict__ feats, const float* __restrict__ wiht,
    const float* __restrict__ bih, float* __restrict__ gi) {
    int bt0 = blockIdx.x * 16;            // 512 blocks
    int g = blockIdx.y * 256 + threadIdx.x;  // 3 groups
    float acc[16];
    float bv = bih[g];
#pragma unroll
    for (int i = 0; i < 16; ++i) acc[i] = bv;
    for (int c = 0; c < CC; ++c) {
        float wv = wiht[c * GG + g];
#pragma unroll
        for (int i = 0; i < 16; ++i) acc[i] += feats[(size_t)(bt0 + i) * CC + c] * wv;
    }
#pragma unroll
    for (int i = 0; i < 16; ++i) gi[(size_t)(bt0 + i) * GG + g] = acc[i];
}

// ---------------- GRU step ----------------
// 16 blocks; block j owns h columns [j*16, j*16+16) => gh rows col, 256+col, 512+col
__global__ __launch_bounds__(256) void gru_step_kernel(
    const float* __restrict__ gi, const float* __restrict__ whh,
    const float* __restrict__ bhh, const float* __restrict__ wcls,
    const float* __restrict__ bcls, const float* __restrict__ hin,
    float* __restrict__ hout, float* __restrict__ out, int s) {
    int j = blockIdx.x;       // 0..15
    int t = threadIdx.x;      // 0..255
    __shared__ float lds_w[48 * 260];     // rows: [0,16)=r,[16,32)=z,[32,48)=n ; stride 260 kills bank conflicts
    __shared__ float lds_hn[16 * 17];

    // stage this block's 48 w_hh rows (48 KB) into LDS, coalesced float4
#pragma unroll
    for (int i = 0; i < 12; ++i) {
        int q = t + i * 256;              // 3072 float4 total
        int row = q >> 6, col4 = q & 63;
        int slice = row >> 4, within = row & 15;
        int g = slice * 256 + j * 16 + within;
        float4 wv = ((const float4*)whh)[g * 64 + col4];
        *(float4*)&lds_w[row * 260 + col4 * 4] = wv;
    }
    __syncthreads();

    int b = t & 15, c = t >> 4;
    int col = j * 16 + c;
    float a0 = bhh[col], a1 = bhh[256 + col], a2 = bhh[512 + col];
    const float4* hv4 = (const float4*)hin;   // h is 16 KB: L1-resident
#pragma unroll 8
    for (int kq = 0; kq < 64; ++kq) {
        float4 hv = hv4[b * 64 + kq];
        float4 w0 = *(const float4*)&lds_w[c * 260 + kq * 4];
        float4 w1 = *(const float4*)&lds_w[(16 + c) * 260 + kq * 4];
        float4 w2 = *(const float4*)&lds_w[(32 + c) * 260 + kq * 4];
        a0 += hv.x * w0.x + hv.y * w0.y + hv.z * w0.z + hv.w * w0.w;
        a1 += hv.x * w1.x + hv.y * w1.y + hv.z * w1.z + hv.w * w1.w;
        a2 += hv.x * w2.x + hv.y * w2.y + hv.z * w2.z + hv.w * w2.w;
    }
    int bt = b * TT + s;
    float gir = gi[(size_t)bt * GG + col];
    float giz = gi[(size_t)bt * GG + 256 + col];
    float gin = gi[(size_t)bt * GG + 512 + col];
    float r = 1.f / (1.f + expf(-(gir + a0)));
    float z = 1.f / (1.f + expf(-(giz + a1)));
    float n = tanhf(gin + r * a2);
    float hold = hin[b * 256 + col];
    float hnew = (1.f - z) * n + z * hold;
    hout[b * 256 + col] = hnew;
    lds_hn[b * 17 + c] = hnew;
    __syncthreads();

    // classifier partial: block j contributes its 16 columns, atomic into zeroed d_out
    int b2 = t & 15, nb = t >> 4;
    float acc = (j == 0) ? bcls[nb] : 0.f;
#pragma unroll
    for (int c2 = 0; c2 < 16; ++c2)
        acc += lds_hn[b2 * 17 + c2] * wcls[nb * 256 + j * 16 + c2];
    atomicAdd(&out[((size_t)b2 * TT + s) * NB + nb], acc);
}

extern "C" void kernel_launch(void* const* d_in, const int* in_sizes, int n_in,
                              void* d_out, int out_size, void* d_ws, size_t ws_size,
                              hipStream_t stream) {
    const float* x    = (const float*)d_in[0];
    const float* w1   = (const float*)d_in[1];
    const float* b1   = (const float*)d_in[2];
    const float* g1   = (const float*)d_in[3];
    const float* bt1  = (const float*)d_in[4];
    const float* m1   = (const float*)d_in[5];
    const float* v1   = (const float*)d_in[6];
    const float* w2   = (const float*)d_in[7];
    const float* b2   = (const float*)d_in[8];
    const float* g2   = (const float*)d_in[9];
    const float* bt2  = (const float*)d_in[10];
    const float* m2   = (const float*)d_in[11];
    const float* v2   = (const float*)d_in[12];
    const float* w3   = (const float*)d_in[13];
    const float* b3   = (const float*)d_in[14];
    const float* g3   = (const float*)d_in[15];
    const float* bt3  = (const float*)d_in[16];
    const float* m3   = (const float*)d_in[17];
    const float* v3   = (const float*)d_in[18];
    const float* wih  = (const float*)d_in[19];
    const float* whh  = (const float*)d_in[20];
    const float* bih  = (const float*)d_in[21];
    const float* bhh  = (const float*)d_in[22];
    const float* wcls = (const float*)d_in[23];
    const float* bcls = (const float*)d_in[24];

    float* ws   = (float*)d_ws;
    float* out1 = ws + O_OUT1;
    float* out2 = ws + O_OUT2;
    float* out3 = ws + O_OUT3;
    float* gi   = ws + O_GI;      // aliases out1 (out1 dead after conv2)
    float* w2t  = ws + O_W2T;
    float* w3t  = ws + O_W3T;
    float* wiht = ws + O_WIHT;
    float* hbuf = ws + O_HBUF;
    float* fout = (float*)d_out;

    // zero output accumulator + initial hidden state
    hipMemsetAsync(d_out, 0, (size_t)BB * TT * NB * sizeof(float), stream);
    hipMemsetAsync(hbuf, 0, (size_t)BB * HH * sizeof(float), stream);

    // weight transposes
    transpose_w_kernel<<<6400, 256, 0, stream>>>(w2, w2t);
    transpose_w_kernel<<<6400, 256, 0, stream>>>(w3, w3t);
    transpose_wih_kernel<<<768, 256, 0, stream>>>(wih, wiht);

    // conv stack
    conv1_kernel<<<dim3(512, 16), 256, 0, stream>>>(x, w1, b1, g1, bt1, m1, v1, out1);
    conv2_kernel<<<dim3(128, 16, 4), 256, 0, stream>>>(out1, w2t, b2, g2, bt2, m2, v2, out2);
    conv3_kernel<<<dim3(128, 16, 4), 256, 0, stream>>>(out2, w3t, b3, g3, bt3, m3, v3, out3);

    // input-to-hidden GEMM (writes over out1 region; conv2 already consumed it)
    gi_kernel<<<dim3(512, 3), 256, 0, stream>>>(out3, wiht, bih, gi);

    // sequential GRU scan: one launch per timestep, ping-pong h buffers
    for (int s = 0; s < TT; ++s) {
        const float* hi = hbuf + (size_t)(s & 1) * (BB * HH);
        float* ho = hbuf + (size_t)((s + 1) & 1) * (BB * HH);
        gru_step_kernel<<<16, 256, 0, stream>>>(gi, whh, bhh, wcls, bcls, hi, ho, fout, s);
    }
}